// Round 5
// baseline (706.950 us; speedup 1.0000x reference)
//
#include <hip/hip_runtime.h>
#include <math.h>

#define NB 8
#define NC 64
#define NH 256
#define NW 256
#define NHW 65536
#define NM 32
#define NPS 4194304   // C*H*W per sample
#define GN_EPS 1e-5f
#define OMEGA 0.0245436926061703f  // 2*pi/256

typedef short shortx8 __attribute__((ext_vector_type(8)));
typedef float floatx4 __attribute__((ext_vector_type(4)));

__device__ __forceinline__ float gelu_f(float v) {
    return 0.5f * v * (1.0f + erff(v * 0.7071067811865475f));
}

__device__ __forceinline__ unsigned short f2bf(float f) {
    unsigned u = __builtin_bit_cast(unsigned, f);
    u = (u + 0x7fffu + ((u >> 16) & 1u)) >> 16;
    return (unsigned short)u;
}

__device__ __forceinline__ float bf2f(unsigned short u) {
    return __builtin_bit_cast(float, ((unsigned)u) << 16);
}

// ---------------- K0: zero GN acc, FiLM gamma/beta, pack MLP weights to bf16 hi/lo
__global__ void k0_init(const float* __restrict__ t_in,
                        const float* __restrict__ gamma_w, const float* __restrict__ gamma_b,
                        const float* __restrict__ beta_w, const float* __restrict__ beta_b,
                        const float* __restrict__ mlp_w1, const float* __restrict__ mlp_w2,
                        float* __restrict__ gn_acc, float* __restrict__ gamma_bc,
                        float* __restrict__ beta_bc,
                        unsigned short* __restrict__ w1p_h, unsigned short* __restrict__ w1p_l,
                        unsigned short* __restrict__ w2p_h, unsigned short* __restrict__ w2p_l) {
    int t = threadIdx.x;
    if (t < 32) gn_acc[t] = 0.f;
    for (int idx = t; idx < NB * NC; idx += 256) {
        int b = idx >> 6, o = idx & 63;
        float g = gamma_b[o], be = beta_b[o];
        for (int c = 0; c < NC; ++c) {
            float tv = t_in[b * NC + c];
            g += gamma_w[o * NC + c] * tv;
            be += beta_w[o * NC + c] * tv;
        }
        gamma_bc[idx] = g;
        beta_bc[idx] = be;
    }
    for (int idx = t; idx < 2048; idx += 256) {
        float wv1 = mlp_w1[idx];
        unsigned short h1 = f2bf(wv1);
        w1p_h[idx] = h1;
        w1p_l[idx] = f2bf(wv1 - bf2f(h1));
        float wv2 = mlp_w2[idx];
        unsigned short h2 = f2bf(wv2);
        w2p_h[idx] = h2;
        w2p_l[idx] = f2bf(wv2 - bf2f(h2));
    }
}

// ---------------- KT: precompute all DFT twiddle matrices as bf16 hi/lo
__global__ __launch_bounds__(256) void k_tw(unsigned short* __restrict__ t1h,
                                            unsigned short* __restrict__ t1l,
                                            unsigned short* __restrict__ uh,
                                            unsigned short* __restrict__ ul,
                                            unsigned short* __restrict__ m2h,
                                            unsigned short* __restrict__ m2l,
                                            unsigned short* __restrict__ m4h,
                                            unsigned short* __restrict__ m4l) {
    int idx = blockIdx.x * 256 + threadIdx.x;   // 0..65535
    if (idx < 16384) {
        int n = idx >> 8, w = idx & 255;
        float ph = OMEGA * (float)(((n & 31) * w) & 255);
        float s, c;
        sincosf(ph, &s, &c);
        float v = (n < 32) ? c : -s;
        unsigned short h = f2bf(v);
        t1h[idx] = h;
        t1l[idx] = f2bf(v - bf2f(h));

        int w2 = idx >> 6, k = idx & 63;
        int k31 = k & 31;
        float m = (k31 == 0) ? 1.f : 2.f;
        float ph2 = OMEGA * (float)((k31 * w2) & 255);
        sincosf(ph2, &s, &c);
        float v2 = (k < 32) ? m * c : -m * s;
        h = f2bf(v2);
        uh[idx] = h;
        ul[idx] = f2bf(v2 - bf2f(h));
    }
    {
        int m = idx >> 9, k = idx & 511;
        int j = m & 63;
        int f = (j < 32) ? j : 192 + j;
        int h256 = k & 255;
        float s, c;
        sincosf(OMEGA * (float)((f * h256) & 255), &s, &c);
        float v = (m < 64) ? ((k < 256) ? c : s) : ((k < 256) ? -s : c);
        unsigned short hh = f2bf(v);
        m2h[idx] = hh;
        m2l[idx] = f2bf(v - bf2f(hh));
    }
    {
        const float sc = 1.0f / 65536.0f;
        int m = idx >> 7, k = idx & 127;
        int h256 = m & 255;
        int j = k & 63;
        int f = (j < 32) ? j : 192 + j;
        float s, c;
        sincosf(OMEGA * (float)((f * h256) & 255), &s, &c);
        float v = ((m < 256) ? ((k < 64) ? c : -s) : ((k < 64) ? s : c)) * sc;
        unsigned short hh = f2bf(v);
        m4h[idx] = hh;
        m4l[idx] = f2bf(v - bf2f(hh));
    }
}

// ---------------- K1: real DFT along W via split-bf16 MFMA GEMM.
__global__ __launch_bounds__(256, 4) void k1_dftw(const float* __restrict__ x,
                                                  const unsigned short* __restrict__ t1h,
                                                  const unsigned short* __restrict__ t1l,
                                                  float* __restrict__ xw_re,
                                                  float* __restrict__ xw_im) {
    __shared__ unsigned short a_h[128 * 72];
    __shared__ unsigned short a_l[128 * 72];
    int blk = blockIdx.x;          // 1024 = 512 bc * 2 row-halves
    int bc = blk >> 1;
    int h0 = (blk & 1) * 128;
    const float* src = x + (size_t)bc * NHW + (size_t)h0 * NW;
    int t = threadIdx.x;
    int lane = t & 63, wv = t >> 6, lm = lane & 15, lg = lane >> 4;

    floatx4 acc[2][4] = {};
#pragma unroll
    for (int ks = 0; ks < 4; ++ks) {
        if (ks) __syncthreads();
        for (int i = t; i < 2048; i += 256) {
            int r = i >> 4;
            int c4 = (i & 15) << 2;
            float4 v = *(const float4*)&src[(size_t)r * NW + (ks << 6) + c4];
            int off = r * 72 + c4;
            ushort4 h4, l4;
            h4.x = f2bf(v.x); l4.x = f2bf(v.x - bf2f(h4.x));
            h4.y = f2bf(v.y); l4.y = f2bf(v.y - bf2f(h4.y));
            h4.z = f2bf(v.z); l4.z = f2bf(v.z - bf2f(h4.z));
            h4.w = f2bf(v.w); l4.w = f2bf(v.w - bf2f(h4.w));
            *(ushort4*)&a_h[off] = h4;
            *(ushort4*)&a_l[off] = l4;
        }
        __syncthreads();
#pragma unroll
        for (int kk = 0; kk < 2; ++kk) {
            shortx8 ah[2], al[2], bh[4], bl[4];
#pragma unroll
            for (int mt = 0; mt < 2; ++mt) {
                int off = (wv * 32 + mt * 16 + lm) * 72 + kk * 32 + lg * 8;
                ah[mt] = *(const shortx8*)&a_h[off];
                al[mt] = *(const shortx8*)&a_l[off];
            }
#pragma unroll
            for (int nt = 0; nt < 4; ++nt) {
                int off = (nt * 16 + lm) * 256 + ks * 64 + kk * 32 + lg * 8;
                bh[nt] = *(const shortx8*)&t1h[off];
                bl[nt] = *(const shortx8*)&t1l[off];
            }
#pragma unroll
            for (int mt = 0; mt < 2; ++mt)
#pragma unroll
                for (int nt = 0; nt < 4; ++nt) {
                    acc[mt][nt] = __builtin_amdgcn_mfma_f32_16x16x32_bf16(ah[mt], bh[nt], acc[mt][nt], 0, 0, 0);
                    acc[mt][nt] = __builtin_amdgcn_mfma_f32_16x16x32_bf16(ah[mt], bl[nt], acc[mt][nt], 0, 0, 0);
                    acc[mt][nt] = __builtin_amdgcn_mfma_f32_16x16x32_bf16(al[mt], bh[nt], acc[mt][nt], 0, 0, 0);
                }
        }
    }
    size_t rowg = (size_t)bc * NH + h0;
#pragma unroll
    for (int mt = 0; mt < 2; ++mt)
#pragma unroll
        for (int nt = 0; nt < 4; ++nt) {
            int n = nt * 16 + lm;
            float* dst = (n < 32) ? xw_re : xw_im;
            int kx = n & 31;
#pragma unroll
            for (int r = 0; r < 4; ++r) {
                int row = wv * 32 + mt * 16 + lg * 4 + r;
                dst[(rowg + row) * NM + kx] = acc[mt][nt][r];
            }
        }
}

// ---------------- K2: DFT along H via split-bf16 MFMA GEMM.
__global__ __launch_bounds__(256, 2) void k2_dfth(const float* __restrict__ xw_re,
                                                  const float* __restrict__ xw_im,
                                                  const unsigned short* __restrict__ m2h,
                                                  const unsigned short* __restrict__ m2l,
                                                  float* __restrict__ xf_re,
                                                  float* __restrict__ xf_im) {
    __shared__ unsigned short bt_h[32 * 520];
    __shared__ unsigned short bt_l[32 * 520];
    int bc = blockIdx.x;
    size_t base = (size_t)bc * (NH * NM);
    int t = threadIdx.x;
    for (int idx4 = t; idx4 < 2048; idx4 += 256) {
        int h = idx4 >> 3;
        int kxg = (idx4 & 7) << 2;
        float4 vr = ((const float4*)(xw_re + base))[idx4];
        float4 vi = ((const float4*)(xw_im + base))[idx4];
        float fr[4] = {vr.x, vr.y, vr.z, vr.w};
        float fi[4] = {vi.x, vi.y, vi.z, vi.w};
#pragma unroll
        for (int q = 0; q < 4; ++q) {
            int rowo = (kxg + q) * 520;
            unsigned short hh = f2bf(fr[q]);
            bt_h[rowo + h] = hh;
            bt_l[rowo + h] = f2bf(fr[q] - bf2f(hh));
            hh = f2bf(fi[q]);
            bt_h[rowo + 256 + h] = hh;
            bt_l[rowo + 256 + h] = f2bf(fi[q] - bf2f(hh));
        }
    }
    __syncthreads();

    int lane = t & 63, wv = t >> 6, lm = lane & 15, lg = lane >> 4;
    floatx4 acc[2][2] = {};
#pragma unroll
    for (int ks = 0; ks < 16; ++ks) {
        shortx8 bh[2], bl[2], ah[2], al[2];
#pragma unroll
        for (int nt = 0; nt < 2; ++nt) {
            int off = (nt * 16 + lm) * 520 + ks * 32 + lg * 8;
            bh[nt] = *(const shortx8*)&bt_h[off];
            bl[nt] = *(const shortx8*)&bt_l[off];
        }
#pragma unroll
        for (int mt = 0; mt < 2; ++mt) {
            int off = (wv * 32 + mt * 16 + lm) * 512 + ks * 32 + lg * 8;
            ah[mt] = *(const shortx8*)&m2h[off];
            al[mt] = *(const shortx8*)&m2l[off];
        }
#pragma unroll
        for (int mt = 0; mt < 2; ++mt)
#pragma unroll
            for (int nt = 0; nt < 2; ++nt) {
                acc[mt][nt] = __builtin_amdgcn_mfma_f32_16x16x32_bf16(ah[mt], bh[nt], acc[mt][nt], 0, 0, 0);
                acc[mt][nt] = __builtin_amdgcn_mfma_f32_16x16x32_bf16(ah[mt], bl[nt], acc[mt][nt], 0, 0, 0);
                acc[mt][nt] = __builtin_amdgcn_mfma_f32_16x16x32_bf16(al[mt], bh[nt], acc[mt][nt], 0, 0, 0);
            }
    }
    size_t ob = (size_t)bc * 2048;
#pragma unroll
    for (int mt = 0; mt < 2; ++mt)
#pragma unroll
        for (int nt = 0; nt < 2; ++nt) {
            int n = nt * 16 + lm;
#pragma unroll
            for (int r = 0; r < 4; ++r) {
                int row = wv * 32 + mt * 16 + lg * 4 + r;
                float* dst = (row < 64) ? xf_re : xf_im;
                dst[ob + (row & 63) * 32 + n] = acc[mt][nt][r];
            }
        }
}

// ---------------- K3: per-mode complex channel mix.  Yf[b][o][ky][kx]
__global__ __launch_bounds__(256) void k3_mix(const float* __restrict__ xf_re,
                                              const float* __restrict__ xf_im,
                                              const float* __restrict__ w1r, const float* __restrict__ w1i,
                                              const float* __restrict__ w2r, const float* __restrict__ w2i,
                                              float* __restrict__ yf_re, float* __restrict__ yf_im) {
    __shared__ float xr_l[4 * 64 * 32];
    __shared__ float xi_l[4 * 64 * 32];
    int blk = blockIdx.x;          // ((ky*8 + oct)*2 + bh)
    int bh = blk & 1;
    int oct = (blk >> 1) & 7;
    int ky = blk >> 4;
    for (int idx = threadIdx.x; idx < 4 * 64 * 32; idx += 256) {
        int bb = idx >> 11;
        int i = (idx >> 5) & 63;
        int kx = idx & 31;
        size_t g = ((size_t)((bh * 4 + bb) * 64 + i) * 64 + ky) * 32 + kx;
        xr_l[idx] = xf_re[g];
        xi_l[idx] = xf_im[g];
    }
    __syncthreads();
    const float* wr = (ky < 32) ? w1r : w2r;
    const float* wi = (ky < 32) ? w1i : w2i;
    int kyl = ky & 31;
    int t = threadIdx.x;
    int kx = t & 31, oo = t >> 5;
    int o = oct * 8 + oo;
    float accr[4] = {0.f, 0.f, 0.f, 0.f};
    float acci[4] = {0.f, 0.f, 0.f, 0.f};
    for (int i = 0; i < 64; ++i) {
        size_t wbase = ((size_t)(i * 64 + o) * 32 + kyl) * 32 + kx;
        float wrv = wr[wbase];
        float wiv = wi[wbase];
#pragma unroll
        for (int bb = 0; bb < 4; ++bb) {
            float xr = xr_l[(bb * 64 + i) * 32 + kx];
            float xi = xi_l[(bb * 64 + i) * 32 + kx];
            accr[bb] += xr * wrv - xi * wiv;
            acci[bb] += xr * wiv + xi * wrv;
        }
    }
#pragma unroll
    for (int bb = 0; bb < 4; ++bb) {
        int b = bh * 4 + bb;
        size_t g = ((size_t)(b * 64 + o) * 64 + ky) * 32 + kx;
        yf_re[g] = accr[bb];
        yf_im[g] = acci[bb];
    }
}

// ---------------- K4: inverse DFT along H via split-bf16 MFMA GEMM.
__global__ __launch_bounds__(256, 2) void k4_idfth(const float* __restrict__ yf_re,
                                                   const float* __restrict__ yf_im,
                                                   const unsigned short* __restrict__ m4h,
                                                   const unsigned short* __restrict__ m4l,
                                                   float* __restrict__ yh_re,
                                                   float* __restrict__ yh_im) {
    __shared__ unsigned short bt_h[32 * 136];
    __shared__ unsigned short bt_l[32 * 136];
    int bc = blockIdx.x;
    size_t base = (size_t)bc * 2048;
    int t = threadIdx.x;
    for (int idx4 = t; idx4 < 512; idx4 += 256) {
        int j = idx4 >> 3;
        int kxg = (idx4 & 7) << 2;
        float4 vr = ((const float4*)(yf_re + base))[idx4];
        float4 vi = ((const float4*)(yf_im + base))[idx4];
        float fr[4] = {vr.x, vr.y, vr.z, vr.w};
        float fi[4] = {vi.x, vi.y, vi.z, vi.w};
#pragma unroll
        for (int q = 0; q < 4; ++q) {
            int rowo = (kxg + q) * 136;
            unsigned short hh = f2bf(fr[q]);
            bt_h[rowo + j] = hh;
            bt_l[rowo + j] = f2bf(fr[q] - bf2f(hh));
            hh = f2bf(fi[q]);
            bt_h[rowo + 64 + j] = hh;
            bt_l[rowo + 64 + j] = f2bf(fi[q] - bf2f(hh));
        }
    }
    __syncthreads();

    int lane = t & 63, wv = t >> 6, lm = lane & 15, lg = lane >> 4;
    floatx4 acc[8][2] = {};
#pragma unroll
    for (int ks = 0; ks < 4; ++ks) {
        shortx8 bh[2], bl[2];
#pragma unroll
        for (int nt = 0; nt < 2; ++nt) {
            int off = (nt * 16 + lm) * 136 + ks * 32 + lg * 8;
            bh[nt] = *(const shortx8*)&bt_h[off];
            bl[nt] = *(const shortx8*)&bt_l[off];
        }
#pragma unroll
        for (int mt = 0; mt < 8; ++mt) {
            int off = (wv * 128 + mt * 16 + lm) * 128 + ks * 32 + lg * 8;
            shortx8 ah = *(const shortx8*)&m4h[off];
            shortx8 al = *(const shortx8*)&m4l[off];
#pragma unroll
            for (int nt = 0; nt < 2; ++nt) {
                acc[mt][nt] = __builtin_amdgcn_mfma_f32_16x16x32_bf16(ah, bh[nt], acc[mt][nt], 0, 0, 0);
                acc[mt][nt] = __builtin_amdgcn_mfma_f32_16x16x32_bf16(ah, bl[nt], acc[mt][nt], 0, 0, 0);
                acc[mt][nt] = __builtin_amdgcn_mfma_f32_16x16x32_bf16(al, bh[nt], acc[mt][nt], 0, 0, 0);
            }
        }
    }
    size_t ob = (size_t)bc * (NH * NM);
#pragma unroll
    for (int mt = 0; mt < 8; ++mt)
#pragma unroll
        for (int nt = 0; nt < 2; ++nt) {
            int n = nt * 16 + lm;
#pragma unroll
            for (int r = 0; r < 4; ++r) {
                int row = wv * 128 + mt * 16 + lg * 4 + r;
                float* dst = (row < 256) ? yh_re : yh_im;
                dst[ob + (row & 255) * 32 + n] = acc[mt][nt][r];
            }
        }
}

// ---------------- K5: inverse real DFT along W via split-bf16 MFMA + GN1 stats.
__global__ __launch_bounds__(256, 2) void k5_irfftw(const float* __restrict__ yh_re,
                                                    const float* __restrict__ yh_im,
                                                    const unsigned short* __restrict__ uh,
                                                    const unsigned short* __restrict__ ul,
                                                    float* __restrict__ yout,
                                                    float* __restrict__ gn_acc) {
    __shared__ unsigned short a_h[128 * 72];
    __shared__ unsigned short a_l[128 * 72];
    __shared__ float red[8];
    int blk = blockIdx.x;          // 1024 blocks of 128 rows
    size_t row0 = (size_t)blk * 128;
    int t = threadIdx.x;

    for (int i = t; i < 1024; i += 256) {
        int r = i >> 3;
        int c4 = (i & 7) << 2;
        float4 vr = *(const float4*)&yh_re[(row0 + r) * NM + c4];
        float4 vi = *(const float4*)&yh_im[(row0 + r) * NM + c4];
        int offr = r * 72 + c4;
        ushort4 h4, l4;
        h4.x = f2bf(vr.x); l4.x = f2bf(vr.x - bf2f(h4.x));
        h4.y = f2bf(vr.y); l4.y = f2bf(vr.y - bf2f(h4.y));
        h4.z = f2bf(vr.z); l4.z = f2bf(vr.z - bf2f(h4.z));
        h4.w = f2bf(vr.w); l4.w = f2bf(vr.w - bf2f(h4.w));
        *(ushort4*)&a_h[offr] = h4;
        *(ushort4*)&a_l[offr] = l4;
        h4.x = f2bf(vi.x); l4.x = f2bf(vi.x - bf2f(h4.x));
        h4.y = f2bf(vi.y); l4.y = f2bf(vi.y - bf2f(h4.y));
        h4.z = f2bf(vi.z); l4.z = f2bf(vi.z - bf2f(h4.z));
        h4.w = f2bf(vi.w); l4.w = f2bf(vi.w - bf2f(h4.w));
        *(ushort4*)&a_h[offr + 32] = h4;
        *(ushort4*)&a_l[offr + 32] = l4;
    }
    __syncthreads();

    int lane = t & 63, wv = t >> 6, lm = lane & 15, lg = lane >> 4;
    floatx4 acc[2][16] = {};
#pragma unroll
    for (int kk = 0; kk < 2; ++kk) {
        shortx8 ah[2], al[2];
#pragma unroll
        for (int mt = 0; mt < 2; ++mt) {
            int off = (wv * 32 + mt * 16 + lm) * 72 + kk * 32 + lg * 8;
            ah[mt] = *(const shortx8*)&a_h[off];
            al[mt] = *(const shortx8*)&a_l[off];
        }
#pragma unroll
        for (int nt = 0; nt < 16; ++nt) {
            int w = nt * 16 + lm;
            shortx8 bh = *(const shortx8*)&uh[w * 64 + kk * 32 + lg * 8];
            shortx8 bl = *(const shortx8*)&ul[w * 64 + kk * 32 + lg * 8];
#pragma unroll
            for (int mt = 0; mt < 2; ++mt) {
                acc[mt][nt] = __builtin_amdgcn_mfma_f32_16x16x32_bf16(ah[mt], bh, acc[mt][nt], 0, 0, 0);
                acc[mt][nt] = __builtin_amdgcn_mfma_f32_16x16x32_bf16(ah[mt], bl, acc[mt][nt], 0, 0, 0);
                acc[mt][nt] = __builtin_amdgcn_mfma_f32_16x16x32_bf16(al[mt], bh, acc[mt][nt], 0, 0, 0);
            }
        }
    }

    float sum = 0.f, sq = 0.f;
#pragma unroll
    for (int mt = 0; mt < 2; ++mt)
#pragma unroll
        for (int nt = 0; nt < 16; ++nt) {
            int w = nt * 16 + lm;
#pragma unroll
            for (int r = 0; r < 4; ++r) {
                int row = wv * 32 + mt * 16 + lg * 4 + r;
                float v = acc[mt][nt][r];
                yout[(row0 + row) * NW + w] = v;
                sum += v;
                sq += v * v;
            }
        }
#pragma unroll
    for (int off = 32; off > 0; off >>= 1) {
        sum += __shfl_down(sum, off);
        sq += __shfl_down(sq, off);
    }
    if (lane == 0) { red[wv] = sum; red[4 + wv] = sq; }
    __syncthreads();
    if (t == 0) {
        int b = blk >> 7;
        atomicAdd(&gn_acc[b * 4 + 0], red[0] + red[1] + red[2] + red[3]);
        atomicAdd(&gn_acc[b * 4 + 1], red[4] + red[5] + red[6] + red[7]);
    }
}

// ---------------- K6: GN1 + residual + gelu + MLP via SPLIT-BF16 MFMA + GN2 stats
// This round: stage-1 A-fragments built IN REGISTERS (each (pix,ch) value is
// needed by exactly one lane) — removes the vbuf LDS tile (36.9KB) and its
// 33.5M bank conflicts (round-4 regression), LDS 77.8KB -> 40.9KB -> 3 blk/CU.
// LDS layout (byte offsets):
//   w1_h @0     32 x 72 bf16 = 4608
//   w1_l @4608
//   hbuf_h @9216  128 x 40 bf16 = 10240
//   hbuf_l @19456
//   w2_h @29696  64 x 40 bf16 = 5120
//   w2_l @34816                         (end 39936)
//   params @39936 nw,nb(64ea) b1(32) b2(64) red(8) = 928  (end 40864)
//   outbuf @0     64 x 132 f32 = 33792  (aliases w1/hbuf/w2 after final sync)
__global__ __launch_bounds__(256, 3) void k6_mlp(const float* __restrict__ x,
                                                 const float* __restrict__ norm1_w,
                                                 const float* __restrict__ norm1_b,
                                                 const unsigned short* __restrict__ w1p_h,
                                                 const unsigned short* __restrict__ w1p_l,
                                                 const unsigned short* __restrict__ w2p_h,
                                                 const unsigned short* __restrict__ w2p_l,
                                                 const float* __restrict__ mlp_b1,
                                                 const float* __restrict__ mlp_b2,
                                                 float* __restrict__ y,
                                                 float* __restrict__ gn_acc) {
    __shared__ __align__(16) unsigned char smem[40864];
    unsigned short* w1_h   = (unsigned short*)smem;
    unsigned short* w1_l   = (unsigned short*)(smem + 4608);
    unsigned short* hbuf_h = (unsigned short*)(smem + 9216);
    unsigned short* hbuf_l = (unsigned short*)(smem + 19456);
    unsigned short* w2_h   = (unsigned short*)(smem + 29696);
    unsigned short* w2_l   = (unsigned short*)(smem + 34816);
    float* outbuf = (float*)smem;                 // alias (phase 2)
    float* nwl = (float*)(smem + 39936);
    float* nbl = nwl + 64;
    float* b1l = nbl + 64;
    float* b2l = b1l + 32;
    float* red = b2l + 64;

    int t = threadIdx.x;
    int blk = blockIdx.x;
    int b = blk >> 9;                  // 512 blocks per sample
    int pixbase = (blk & 511) * 128;
    size_t bbase = (size_t)b * NC * NHW + pixbase;

    if (t < 64) { nwl[t] = norm1_w[t]; nbl[t] = norm1_b[t]; b2l[t] = mlp_b2[t]; }
    if (t >= 64 && t < 96) b1l[t - 64] = mlp_b1[t - 64];
#pragma unroll
    for (int idx4 = t; idx4 < 512; idx4 += 256) {
        int r1 = idx4 >> 4, c1 = (idx4 & 15) << 2;
        *(ushort4*)&w1_h[r1 * 72 + c1] = ((const ushort4*)w1p_h)[idx4];
        *(ushort4*)&w1_l[r1 * 72 + c1] = ((const ushort4*)w1p_l)[idx4];
        int r2 = idx4 >> 3, c2 = (idx4 & 7) << 2;
        *(ushort4*)&w2_h[r2 * 40 + c2] = ((const ushort4*)w2p_h)[idx4];
        *(ushort4*)&w2_l[r2 * 40 + c2] = ((const ushort4*)w2p_l)[idx4];
    }
    __syncthreads();   // params/weights visible before use (race fix preserved)

    int lane = t & 63, wv = t >> 6;
    int lm = lane & 15, lg = lane >> 4;

    // --- stage 1 (in registers): v = gelu(gn1(y)*nw+nb + x) for exactly the
    // A-fragment elements this lane owns: rows wv*32+mt*16+lm, ch ks*32+lg*8+j.
    const float invN = 1.0f / (float)NPS;
    float m1 = gn_acc[b * 4 + 0] * invN;
    float var1 = gn_acc[b * 4 + 1] * invN - m1 * m1;
    float rs1 = rsqrtf(var1 + GN_EPS);
    shortx8 ah[2][2], al[2][2];    // [ks][mt]
#pragma unroll
    for (int mt = 0; mt < 2; ++mt) {
        int row = wv * 32 + mt * 16 + lm;
#pragma unroll
        for (int ks = 0; ks < 2; ++ks) {
#pragma unroll
            for (int j = 0; j < 8; ++j) {
                int c = ks * 32 + lg * 8 + j;
                size_t rb = bbase + (size_t)c * NHW + row;
                float yv = y[rb];
                float xv = x[rb];
                float g = (yv - m1) * rs1 * nwl[c] + nbl[c] + xv;
                float vv = gelu_f(g);
                unsigned short vh = f2bf(vv);
                ah[ks][mt][j] = (short)vh;
                al[ks][mt][j] = (short)f2bf(vv - bf2f(vh));
            }
        }
    }

    // --- layer 1 MFMA: h[128x32] = v @ w1^T (3-term split), + b1, gelu -> hbuf
    floatx4 acc1[2][2] = {};
#pragma unroll
    for (int ks = 0; ks < 2; ++ks) {
        shortx8 bh[2], bl[2];
#pragma unroll
        for (int nt = 0; nt < 2; ++nt) {
            int off = (nt * 16 + lm) * 72 + lg * 8 + ks * 32;
            bh[nt] = *(const shortx8*)&w1_h[off];
            bl[nt] = *(const shortx8*)&w1_l[off];
        }
#pragma unroll
        for (int mt = 0; mt < 2; ++mt)
#pragma unroll
            for (int nt = 0; nt < 2; ++nt) {
                acc1[mt][nt] = __builtin_amdgcn_mfma_f32_16x16x32_bf16(ah[ks][mt], bh[nt], acc1[mt][nt], 0, 0, 0);
                acc1[mt][nt] = __builtin_amdgcn_mfma_f32_16x16x32_bf16(ah[ks][mt], bl[nt], acc1[mt][nt], 0, 0, 0);
                acc1[mt][nt] = __builtin_amdgcn_mfma_f32_16x16x32_bf16(al[ks][mt], bh[nt], acc1[mt][nt], 0, 0, 0);
            }
    }
#pragma unroll
    for (int mt = 0; mt < 2; ++mt)
#pragma unroll
        for (int nt = 0; nt < 2; ++nt) {
            float b1v = b1l[nt * 16 + lm];
#pragma unroll
            for (int r = 0; r < 4; ++r) {
                float hv = gelu_f(acc1[mt][nt][r] + b1v);
                unsigned short hh = f2bf(hv);
                int off = (wv * 32 + mt * 16 + lg * 4 + r) * 40 + nt * 16 + lm;
                hbuf_h[off] = hh;
                hbuf_l[off] = f2bf(hv - bf2f(hh));
            }
        }
    __syncthreads();

    // --- layer 2 MFMA: out[128x64] = h @ w2^T (3-term split)
    floatx4 acc2[2][4] = {};
    {
        shortx8 ah2[2], al2[2], bh2[4], bl2[4];
#pragma unroll
        for (int mt = 0; mt < 2; ++mt) {
            int off = (wv * 32 + mt * 16 + lm) * 40 + lg * 8;
            ah2[mt] = *(const shortx8*)&hbuf_h[off];
            al2[mt] = *(const shortx8*)&hbuf_l[off];
        }
#pragma unroll
        for (int nt = 0; nt < 4; ++nt) {
            int off = (nt * 16 + lm) * 40 + lg * 8;
            bh2[nt] = *(const shortx8*)&w2_h[off];
            bl2[nt] = *(const shortx8*)&w2_l[off];
        }
#pragma unroll
        for (int mt = 0; mt < 2; ++mt)
#pragma unroll
            for (int nt = 0; nt < 4; ++nt) {
                acc2[mt][nt] = __builtin_amdgcn_mfma_f32_16x16x32_bf16(ah2[mt], bh2[nt], acc2[mt][nt], 0, 0, 0);
                acc2[mt][nt] = __builtin_amdgcn_mfma_f32_16x16x32_bf16(ah2[mt], bl2[nt], acc2[mt][nt], 0, 0, 0);
                acc2[mt][nt] = __builtin_amdgcn_mfma_f32_16x16x32_bf16(al2[mt], bh2[nt], acc2[mt][nt], 0, 0, 0);
            }
    }
    __syncthreads();   // all w1/hbuf/w2 reads done; outbuf may now clobber

#pragma unroll
    for (int mt = 0; mt < 2; ++mt)
#pragma unroll
        for (int nt = 0; nt < 4; ++nt) {
            int ch = nt * 16 + lm;
            float b2v = b2l[ch];
#pragma unroll
            for (int r = 0; r < 4; ++r)
                outbuf[ch * 132 + wv * 32 + mt * 16 + lg * 4 + r] = acc2[mt][nt][r] + b2v;
        }
    __syncthreads();

    float sum = 0.f, sq = 0.f;
#pragma unroll
    for (int it = 0; it < 8; ++it) {
        int flat = it * 256 + t;
        int c = flat >> 5;
        int p4 = (flat & 31) * 4;
        float4 v = *(const float4*)&outbuf[c * 132 + p4];
        *(float4*)&y[bbase + (size_t)c * NHW + p4] = v;
        sum += v.x + v.y + v.z + v.w;
        sq += v.x * v.x + v.y * v.y + v.z * v.z + v.w * v.w;
    }
#pragma unroll
    for (int off = 32; off > 0; off >>= 1) {
        sum += __shfl_down(sum, off);
        sq += __shfl_down(sq, off);
    }
    if (lane == 0) { red[wv] = sum; red[4 + wv] = sq; }
    __syncthreads();
    if (t == 0) {
        atomicAdd(&gn_acc[b * 4 + 2], red[0] + red[1] + red[2] + red[3]);
        atomicAdd(&gn_acc[b * 4 + 3], red[4] + red[5] + red[6] + red[7]);
    }
}

// ---------------- K7: GN2 + FiLM + gelu(x) skip, elementwise, in-place
__global__ __launch_bounds__(256) void k7_final(const float* __restrict__ x,
                                                const float* __restrict__ gamma_bc,
                                                const float* __restrict__ beta_bc,
                                                const float* __restrict__ gn_acc,
                                                float* __restrict__ y) {
    size_t idx4 = (size_t)blockIdx.x * 256 + threadIdx.x;
    size_t base = idx4 * 4;
    int b = (int)(base >> 22);
    int c = (int)((base >> 16) & 63);
    const float invN = 1.0f / (float)NPS;
    float m2 = gn_acc[b * 4 + 2] * invN;
    float var2 = gn_acc[b * 4 + 3] * invN - m2 * m2;
    float rs2 = rsqrtf(var2 + GN_EPS);
    float g = gamma_bc[b * 64 + c];
    float be = beta_bc[b * 64 + c];
    float4 yv = ((float4*)y)[idx4];
    float4 xv = ((const float4*)x)[idx4];
    yv.x = g * ((yv.x - m2) * rs2) + be + gelu_f(xv.x);
    yv.y = g * ((yv.y - m2) * rs2) + be + gelu_f(xv.y);
    yv.z = g * ((yv.z - m2) * rs2) + be + gelu_f(xv.z);
    yv.w = g * ((yv.w - m2) * rs2) + be + gelu_f(xv.w);
    ((float4*)y)[idx4] = yv;
}

extern "C" void kernel_launch(void* const* d_in, const int* in_sizes, int n_in,
                              void* d_out, int out_size, void* d_ws, size_t ws_size,
                              hipStream_t stream) {
    (void)in_sizes; (void)n_in; (void)out_size; (void)ws_size;
    const float* x       = (const float*)d_in[0];
    const float* t_in    = (const float*)d_in[1];
    const float* w1r     = (const float*)d_in[2];
    const float* w1i     = (const float*)d_in[3];
    const float* w2r     = (const float*)d_in[4];
    const float* w2i     = (const float*)d_in[5];
    const float* norm1_w = (const float*)d_in[6];
    const float* norm1_b = (const float*)d_in[7];
    const float* mlp_w1  = (const float*)d_in[8];
    const float* mlp_b1  = (const float*)d_in[9];
    const float* mlp_w2  = (const float*)d_in[10];
    const float* mlp_b2  = (const float*)d_in[11];
    const float* gamma_w = (const float*)d_in[12];
    const float* gamma_b = (const float*)d_in[13];
    const float* beta_w  = (const float*)d_in[14];
    const float* beta_b  = (const float*)d_in[15];
    float* out = (float*)d_out;
    float* ws  = (float*)d_ws;

    float* gn_acc   = ws;            // 32
    float* gamma_bc = ws + 32;       // 512
    float* beta_bc  = ws + 544;      // 512
    float* xw_re    = ws + 2048;     // 4194304
    float* xw_im    = xw_re + 4194304;
    float* xf_re    = xw_im + 4194304;  // 1048576
    float* xf_im    = xf_re + 1048576;
    float* yf_re    = xf_im + 1048576;
    float* yf_im    = yf_re + 1048576;
    unsigned short* t1h = (unsigned short*)(yf_im + 1048576);
    unsigned short* t1l = t1h + 16384;
    unsigned short* uh  = t1l + 16384;
    unsigned short* ul  = uh + 16384;
    unsigned short* w1p_h = ul + 16384;     // 2048 each
    unsigned short* w1p_l = w1p_h + 2048;
    unsigned short* w2p_h = w1p_l + 2048;
    unsigned short* w2p_l = w2p_h + 2048;
    unsigned short* m2h = w2p_l + 2048;     // 65536 each
    unsigned short* m2l = m2h + 65536;
    unsigned short* m4h = m2l + 65536;
    unsigned short* m4l = m4h + 65536;

    k_tw<<<dim3(256), dim3(256), 0, stream>>>(t1h, t1l, uh, ul, m2h, m2l, m4h, m4l);
    k0_init<<<dim3(1), dim3(256), 0, stream>>>(t_in, gamma_w, gamma_b, beta_w, beta_b,
                                               mlp_w1, mlp_w2,
                                               gn_acc, gamma_bc, beta_bc,
                                               w1p_h, w1p_l, w2p_h, w2p_l);
    k1_dftw<<<dim3(1024), dim3(256), 0, stream>>>(x, t1h, t1l, xw_re, xw_im);
    k2_dfth<<<dim3(512), dim3(256), 0, stream>>>(xw_re, xw_im, m2h, m2l, xf_re, xf_im);
    k3_mix<<<dim3(1024), dim3(256), 0, stream>>>(xf_re, xf_im, w1r, w1i, w2r, w2i,
                                                 yf_re, yf_im);
    k4_idfth<<<dim3(512), dim3(256), 0, stream>>>(yf_re, yf_im, m4h, m4l, xw_re, xw_im);
    k5_irfftw<<<dim3(1024), dim3(256), 0, stream>>>(xw_re, xw_im, uh, ul, out, gn_acc);
    k6_mlp<<<dim3(4096), dim3(256), 0, stream>>>(x, norm1_w, norm1_b,
                                                 w1p_h, w1p_l, w2p_h, w2p_l,
                                                 mlp_b1, mlp_b2, out, gn_acc);
    k7_final<<<dim3(32768), dim3(256), 0, stream>>>(x, gamma_bc, beta_bc, gn_acc, out);
}

// Round 6
// 647.037 us; speedup vs baseline: 1.0926x; 1.0926x over previous
//
#include <hip/hip_runtime.h>
#include <math.h>

#define NB 8
#define NC 64
#define NH 256
#define NW 256
#define NHW 65536
#define NM 32
#define NPS 4194304   // C*H*W per sample
#define GN_EPS 1e-5f
#define OMEGA 0.0245436926061703f  // 2*pi/256

typedef short shortx8 __attribute__((ext_vector_type(8)));
typedef float floatx4 __attribute__((ext_vector_type(4)));

__device__ __forceinline__ float gelu_f(float v) {
    return 0.5f * v * (1.0f + erff(v * 0.7071067811865475f));
}

__device__ __forceinline__ unsigned short f2bf(float f) {
    unsigned u = __builtin_bit_cast(unsigned, f);
    u = (u + 0x7fffu + ((u >> 16) & 1u)) >> 16;
    return (unsigned short)u;
}

__device__ __forceinline__ float bf2f(unsigned short u) {
    return __builtin_bit_cast(float, ((unsigned)u) << 16);
}

// ---------------- K0: zero GN acc, FiLM gamma/beta, pack MLP weights to bf16 hi/lo
__global__ void k0_init(const float* __restrict__ t_in,
                        const float* __restrict__ gamma_w, const float* __restrict__ gamma_b,
                        const float* __restrict__ beta_w, const float* __restrict__ beta_b,
                        const float* __restrict__ mlp_w1, const float* __restrict__ mlp_w2,
                        float* __restrict__ gn_acc, float* __restrict__ gamma_bc,
                        float* __restrict__ beta_bc,
                        unsigned short* __restrict__ w1p_h, unsigned short* __restrict__ w1p_l,
                        unsigned short* __restrict__ w2p_h, unsigned short* __restrict__ w2p_l) {
    int t = threadIdx.x;
    if (t < 32) gn_acc[t] = 0.f;
    for (int idx = t; idx < NB * NC; idx += 256) {
        int b = idx >> 6, o = idx & 63;
        float g = gamma_b[o], be = beta_b[o];
        for (int c = 0; c < NC; ++c) {
            float tv = t_in[b * NC + c];
            g += gamma_w[o * NC + c] * tv;
            be += beta_w[o * NC + c] * tv;
        }
        gamma_bc[idx] = g;
        beta_bc[idx] = be;
    }
    for (int idx = t; idx < 2048; idx += 256) {
        float wv1 = mlp_w1[idx];
        unsigned short h1 = f2bf(wv1);
        w1p_h[idx] = h1;
        w1p_l[idx] = f2bf(wv1 - bf2f(h1));
        float wv2 = mlp_w2[idx];
        unsigned short h2 = f2bf(wv2);
        w2p_h[idx] = h2;
        w2p_l[idx] = f2bf(wv2 - bf2f(h2));
    }
}

// ---------------- KT: precompute all DFT twiddle matrices as bf16 hi/lo
__global__ __launch_bounds__(256) void k_tw(unsigned short* __restrict__ t1h,
                                            unsigned short* __restrict__ t1l,
                                            unsigned short* __restrict__ uh,
                                            unsigned short* __restrict__ ul,
                                            unsigned short* __restrict__ m2h,
                                            unsigned short* __restrict__ m2l,
                                            unsigned short* __restrict__ m4h,
                                            unsigned short* __restrict__ m4l) {
    int idx = blockIdx.x * 256 + threadIdx.x;   // 0..65535
    if (idx < 16384) {
        int n = idx >> 8, w = idx & 255;
        float ph = OMEGA * (float)(((n & 31) * w) & 255);
        float s, c;
        sincosf(ph, &s, &c);
        float v = (n < 32) ? c : -s;
        unsigned short h = f2bf(v);
        t1h[idx] = h;
        t1l[idx] = f2bf(v - bf2f(h));

        int w2 = idx >> 6, k = idx & 63;
        int k31 = k & 31;
        float m = (k31 == 0) ? 1.f : 2.f;
        float ph2 = OMEGA * (float)((k31 * w2) & 255);
        sincosf(ph2, &s, &c);
        float v2 = (k < 32) ? m * c : -m * s;
        h = f2bf(v2);
        uh[idx] = h;
        ul[idx] = f2bf(v2 - bf2f(h));
    }
    {
        int m = idx >> 9, k = idx & 511;
        int j = m & 63;
        int f = (j < 32) ? j : 192 + j;
        int h256 = k & 255;
        float s, c;
        sincosf(OMEGA * (float)((f * h256) & 255), &s, &c);
        float v = (m < 64) ? ((k < 256) ? c : s) : ((k < 256) ? -s : c);
        unsigned short hh = f2bf(v);
        m2h[idx] = hh;
        m2l[idx] = f2bf(v - bf2f(hh));
    }
    {
        const float sc = 1.0f / 65536.0f;
        int m = idx >> 7, k = idx & 127;
        int h256 = m & 255;
        int j = k & 63;
        int f = (j < 32) ? j : 192 + j;
        float s, c;
        sincosf(OMEGA * (float)((f * h256) & 255), &s, &c);
        float v = ((m < 256) ? ((k < 64) ? c : -s) : ((k < 64) ? s : c)) * sc;
        unsigned short hh = f2bf(v);
        m4h[idx] = hh;
        m4l[idx] = f2bf(v - bf2f(hh));
    }
}

// ---------------- K1: real DFT along W via split-bf16 MFMA GEMM.
__global__ __launch_bounds__(256, 4) void k1_dftw(const float* __restrict__ x,
                                                  const unsigned short* __restrict__ t1h,
                                                  const unsigned short* __restrict__ t1l,
                                                  float* __restrict__ xw_re,
                                                  float* __restrict__ xw_im) {
    __shared__ unsigned short a_h[128 * 72];
    __shared__ unsigned short a_l[128 * 72];
    int blk = blockIdx.x;          // 1024 = 512 bc * 2 row-halves
    int bc = blk >> 1;
    int h0 = (blk & 1) * 128;
    const float* src = x + (size_t)bc * NHW + (size_t)h0 * NW;
    int t = threadIdx.x;
    int lane = t & 63, wv = t >> 6, lm = lane & 15, lg = lane >> 4;

    floatx4 acc[2][4] = {};
#pragma unroll
    for (int ks = 0; ks < 4; ++ks) {
        if (ks) __syncthreads();
        for (int i = t; i < 2048; i += 256) {
            int r = i >> 4;
            int c4 = (i & 15) << 2;
            float4 v = *(const float4*)&src[(size_t)r * NW + (ks << 6) + c4];
            int off = r * 72 + c4;
            ushort4 h4, l4;
            h4.x = f2bf(v.x); l4.x = f2bf(v.x - bf2f(h4.x));
            h4.y = f2bf(v.y); l4.y = f2bf(v.y - bf2f(h4.y));
            h4.z = f2bf(v.z); l4.z = f2bf(v.z - bf2f(h4.z));
            h4.w = f2bf(v.w); l4.w = f2bf(v.w - bf2f(h4.w));
            *(ushort4*)&a_h[off] = h4;
            *(ushort4*)&a_l[off] = l4;
        }
        __syncthreads();
#pragma unroll
        for (int kk = 0; kk < 2; ++kk) {
            shortx8 ah[2], al[2], bh[4], bl[4];
#pragma unroll
            for (int mt = 0; mt < 2; ++mt) {
                int off = (wv * 32 + mt * 16 + lm) * 72 + kk * 32 + lg * 8;
                ah[mt] = *(const shortx8*)&a_h[off];
                al[mt] = *(const shortx8*)&a_l[off];
            }
#pragma unroll
            for (int nt = 0; nt < 4; ++nt) {
                int off = (nt * 16 + lm) * 256 + ks * 64 + kk * 32 + lg * 8;
                bh[nt] = *(const shortx8*)&t1h[off];
                bl[nt] = *(const shortx8*)&t1l[off];
            }
#pragma unroll
            for (int mt = 0; mt < 2; ++mt)
#pragma unroll
                for (int nt = 0; nt < 4; ++nt) {
                    acc[mt][nt] = __builtin_amdgcn_mfma_f32_16x16x32_bf16(ah[mt], bh[nt], acc[mt][nt], 0, 0, 0);
                    acc[mt][nt] = __builtin_amdgcn_mfma_f32_16x16x32_bf16(ah[mt], bl[nt], acc[mt][nt], 0, 0, 0);
                    acc[mt][nt] = __builtin_amdgcn_mfma_f32_16x16x32_bf16(al[mt], bh[nt], acc[mt][nt], 0, 0, 0);
                }
        }
    }
    size_t rowg = (size_t)bc * NH + h0;
#pragma unroll
    for (int mt = 0; mt < 2; ++mt)
#pragma unroll
        for (int nt = 0; nt < 4; ++nt) {
            int n = nt * 16 + lm;
            float* dst = (n < 32) ? xw_re : xw_im;
            int kx = n & 31;
#pragma unroll
            for (int r = 0; r < 4; ++r) {
                int row = wv * 32 + mt * 16 + lg * 4 + r;
                dst[(rowg + row) * NM + kx] = acc[mt][nt][r];
            }
        }
}

// ---------------- K2: DFT along H via split-bf16 MFMA GEMM.
__global__ __launch_bounds__(256, 2) void k2_dfth(const float* __restrict__ xw_re,
                                                  const float* __restrict__ xw_im,
                                                  const unsigned short* __restrict__ m2h,
                                                  const unsigned short* __restrict__ m2l,
                                                  float* __restrict__ xf_re,
                                                  float* __restrict__ xf_im) {
    __shared__ unsigned short bt_h[32 * 520];
    __shared__ unsigned short bt_l[32 * 520];
    int bc = blockIdx.x;
    size_t base = (size_t)bc * (NH * NM);
    int t = threadIdx.x;
    for (int idx4 = t; idx4 < 2048; idx4 += 256) {
        int h = idx4 >> 3;
        int kxg = (idx4 & 7) << 2;
        float4 vr = ((const float4*)(xw_re + base))[idx4];
        float4 vi = ((const float4*)(xw_im + base))[idx4];
        float fr[4] = {vr.x, vr.y, vr.z, vr.w};
        float fi[4] = {vi.x, vi.y, vi.z, vi.w};
#pragma unroll
        for (int q = 0; q < 4; ++q) {
            int rowo = (kxg + q) * 520;
            unsigned short hh = f2bf(fr[q]);
            bt_h[rowo + h] = hh;
            bt_l[rowo + h] = f2bf(fr[q] - bf2f(hh));
            hh = f2bf(fi[q]);
            bt_h[rowo + 256 + h] = hh;
            bt_l[rowo + 256 + h] = f2bf(fi[q] - bf2f(hh));
        }
    }
    __syncthreads();

    int lane = t & 63, wv = t >> 6, lm = lane & 15, lg = lane >> 4;
    floatx4 acc[2][2] = {};
#pragma unroll
    for (int ks = 0; ks < 16; ++ks) {
        shortx8 bh[2], bl[2], ah[2], al[2];
#pragma unroll
        for (int nt = 0; nt < 2; ++nt) {
            int off = (nt * 16 + lm) * 520 + ks * 32 + lg * 8;
            bh[nt] = *(const shortx8*)&bt_h[off];
            bl[nt] = *(const shortx8*)&bt_l[off];
        }
#pragma unroll
        for (int mt = 0; mt < 2; ++mt) {
            int off = (wv * 32 + mt * 16 + lm) * 512 + ks * 32 + lg * 8;
            ah[mt] = *(const shortx8*)&m2h[off];
            al[mt] = *(const shortx8*)&m2l[off];
        }
#pragma unroll
        for (int mt = 0; mt < 2; ++mt)
#pragma unroll
            for (int nt = 0; nt < 2; ++nt) {
                acc[mt][nt] = __builtin_amdgcn_mfma_f32_16x16x32_bf16(ah[mt], bh[nt], acc[mt][nt], 0, 0, 0);
                acc[mt][nt] = __builtin_amdgcn_mfma_f32_16x16x32_bf16(ah[mt], bl[nt], acc[mt][nt], 0, 0, 0);
                acc[mt][nt] = __builtin_amdgcn_mfma_f32_16x16x32_bf16(al[mt], bh[nt], acc[mt][nt], 0, 0, 0);
            }
    }
    size_t ob = (size_t)bc * 2048;
#pragma unroll
    for (int mt = 0; mt < 2; ++mt)
#pragma unroll
        for (int nt = 0; nt < 2; ++nt) {
            int n = nt * 16 + lm;
#pragma unroll
            for (int r = 0; r < 4; ++r) {
                int row = wv * 32 + mt * 16 + lg * 4 + r;
                float* dst = (row < 64) ? xf_re : xf_im;
                dst[ob + (row & 63) * 32 + n] = acc[mt][nt][r];
            }
        }
}

// ---------------- K3: per-mode complex channel mix.  Yf[b][o][ky][kx]
__global__ __launch_bounds__(256) void k3_mix(const float* __restrict__ xf_re,
                                              const float* __restrict__ xf_im,
                                              const float* __restrict__ w1r, const float* __restrict__ w1i,
                                              const float* __restrict__ w2r, const float* __restrict__ w2i,
                                              float* __restrict__ yf_re, float* __restrict__ yf_im) {
    __shared__ float xr_l[4 * 64 * 32];
    __shared__ float xi_l[4 * 64 * 32];
    int blk = blockIdx.x;          // ((ky*8 + oct)*2 + bh)
    int bh = blk & 1;
    int oct = (blk >> 1) & 7;
    int ky = blk >> 4;
    for (int idx = threadIdx.x; idx < 4 * 64 * 32; idx += 256) {
        int bb = idx >> 11;
        int i = (idx >> 5) & 63;
        int kx = idx & 31;
        size_t g = ((size_t)((bh * 4 + bb) * 64 + i) * 64 + ky) * 32 + kx;
        xr_l[idx] = xf_re[g];
        xi_l[idx] = xf_im[g];
    }
    __syncthreads();
    const float* wr = (ky < 32) ? w1r : w2r;
    const float* wi = (ky < 32) ? w1i : w2i;
    int kyl = ky & 31;
    int t = threadIdx.x;
    int kx = t & 31, oo = t >> 5;
    int o = oct * 8 + oo;
    float accr[4] = {0.f, 0.f, 0.f, 0.f};
    float acci[4] = {0.f, 0.f, 0.f, 0.f};
    for (int i = 0; i < 64; ++i) {
        size_t wbase = ((size_t)(i * 64 + o) * 32 + kyl) * 32 + kx;
        float wrv = wr[wbase];
        float wiv = wi[wbase];
#pragma unroll
        for (int bb = 0; bb < 4; ++bb) {
            float xr = xr_l[(bb * 64 + i) * 32 + kx];
            float xi = xi_l[(bb * 64 + i) * 32 + kx];
            accr[bb] += xr * wrv - xi * wiv;
            acci[bb] += xr * wiv + xi * wrv;
        }
    }
#pragma unroll
    for (int bb = 0; bb < 4; ++bb) {
        int b = bh * 4 + bb;
        size_t g = ((size_t)(b * 64 + o) * 64 + ky) * 32 + kx;
        yf_re[g] = accr[bb];
        yf_im[g] = acci[bb];
    }
}

// ---------------- K4: inverse DFT along H via split-bf16 MFMA GEMM.
__global__ __launch_bounds__(256, 2) void k4_idfth(const float* __restrict__ yf_re,
                                                   const float* __restrict__ yf_im,
                                                   const unsigned short* __restrict__ m4h,
                                                   const unsigned short* __restrict__ m4l,
                                                   float* __restrict__ yh_re,
                                                   float* __restrict__ yh_im) {
    __shared__ unsigned short bt_h[32 * 136];
    __shared__ unsigned short bt_l[32 * 136];
    int bc = blockIdx.x;
    size_t base = (size_t)bc * 2048;
    int t = threadIdx.x;
    for (int idx4 = t; idx4 < 512; idx4 += 256) {
        int j = idx4 >> 3;
        int kxg = (idx4 & 7) << 2;
        float4 vr = ((const float4*)(yf_re + base))[idx4];
        float4 vi = ((const float4*)(yf_im + base))[idx4];
        float fr[4] = {vr.x, vr.y, vr.z, vr.w};
        float fi[4] = {vi.x, vi.y, vi.z, vi.w};
#pragma unroll
        for (int q = 0; q < 4; ++q) {
            int rowo = (kxg + q) * 136;
            unsigned short hh = f2bf(fr[q]);
            bt_h[rowo + j] = hh;
            bt_l[rowo + j] = f2bf(fr[q] - bf2f(hh));
            hh = f2bf(fi[q]);
            bt_h[rowo + 64 + j] = hh;
            bt_l[rowo + 64 + j] = f2bf(fi[q] - bf2f(hh));
        }
    }
    __syncthreads();

    int lane = t & 63, wv = t >> 6, lm = lane & 15, lg = lane >> 4;
    floatx4 acc[8][2] = {};
#pragma unroll
    for (int ks = 0; ks < 4; ++ks) {
        shortx8 bh[2], bl[2];
#pragma unroll
        for (int nt = 0; nt < 2; ++nt) {
            int off = (nt * 16 + lm) * 136 + ks * 32 + lg * 8;
            bh[nt] = *(const shortx8*)&bt_h[off];
            bl[nt] = *(const shortx8*)&bt_l[off];
        }
#pragma unroll
        for (int mt = 0; mt < 8; ++mt) {
            int off = (wv * 128 + mt * 16 + lm) * 128 + ks * 32 + lg * 8;
            shortx8 ah = *(const shortx8*)&m4h[off];
            shortx8 al = *(const shortx8*)&m4l[off];
#pragma unroll
            for (int nt = 0; nt < 2; ++nt) {
                acc[mt][nt] = __builtin_amdgcn_mfma_f32_16x16x32_bf16(ah, bh[nt], acc[mt][nt], 0, 0, 0);
                acc[mt][nt] = __builtin_amdgcn_mfma_f32_16x16x32_bf16(ah, bl[nt], acc[mt][nt], 0, 0, 0);
                acc[mt][nt] = __builtin_amdgcn_mfma_f32_16x16x32_bf16(al, bh[nt], acc[mt][nt], 0, 0, 0);
            }
        }
    }
    size_t ob = (size_t)bc * (NH * NM);
#pragma unroll
    for (int mt = 0; mt < 8; ++mt)
#pragma unroll
        for (int nt = 0; nt < 2; ++nt) {
            int n = nt * 16 + lm;
#pragma unroll
            for (int r = 0; r < 4; ++r) {
                int row = wv * 128 + mt * 16 + lg * 4 + r;
                float* dst = (row < 256) ? yh_re : yh_im;
                dst[ob + (row & 255) * 32 + n] = acc[mt][nt][r];
            }
        }
}

// ---------------- K5: inverse real DFT along W via split-bf16 MFMA + GN1 stats.
__global__ __launch_bounds__(256, 2) void k5_irfftw(const float* __restrict__ yh_re,
                                                    const float* __restrict__ yh_im,
                                                    const unsigned short* __restrict__ uh,
                                                    const unsigned short* __restrict__ ul,
                                                    float* __restrict__ yout,
                                                    float* __restrict__ gn_acc) {
    __shared__ unsigned short a_h[128 * 72];
    __shared__ unsigned short a_l[128 * 72];
    __shared__ float red[8];
    int blk = blockIdx.x;          // 1024 blocks of 128 rows
    size_t row0 = (size_t)blk * 128;
    int t = threadIdx.x;

    for (int i = t; i < 1024; i += 256) {
        int r = i >> 3;
        int c4 = (i & 7) << 2;
        float4 vr = *(const float4*)&yh_re[(row0 + r) * NM + c4];
        float4 vi = *(const float4*)&yh_im[(row0 + r) * NM + c4];
        int offr = r * 72 + c4;
        ushort4 h4, l4;
        h4.x = f2bf(vr.x); l4.x = f2bf(vr.x - bf2f(h4.x));
        h4.y = f2bf(vr.y); l4.y = f2bf(vr.y - bf2f(h4.y));
        h4.z = f2bf(vr.z); l4.z = f2bf(vr.z - bf2f(h4.z));
        h4.w = f2bf(vr.w); l4.w = f2bf(vr.w - bf2f(h4.w));
        *(ushort4*)&a_h[offr] = h4;
        *(ushort4*)&a_l[offr] = l4;
        h4.x = f2bf(vi.x); l4.x = f2bf(vi.x - bf2f(h4.x));
        h4.y = f2bf(vi.y); l4.y = f2bf(vi.y - bf2f(h4.y));
        h4.z = f2bf(vi.z); l4.z = f2bf(vi.z - bf2f(h4.z));
        h4.w = f2bf(vi.w); l4.w = f2bf(vi.w - bf2f(h4.w));
        *(ushort4*)&a_h[offr + 32] = h4;
        *(ushort4*)&a_l[offr + 32] = l4;
    }
    __syncthreads();

    int lane = t & 63, wv = t >> 6, lm = lane & 15, lg = lane >> 4;
    floatx4 acc[2][16] = {};
#pragma unroll
    for (int kk = 0; kk < 2; ++kk) {
        shortx8 ah[2], al[2];
#pragma unroll
        for (int mt = 0; mt < 2; ++mt) {
            int off = (wv * 32 + mt * 16 + lm) * 72 + kk * 32 + lg * 8;
            ah[mt] = *(const shortx8*)&a_h[off];
            al[mt] = *(const shortx8*)&a_l[off];
        }
#pragma unroll
        for (int nt = 0; nt < 16; ++nt) {
            int w = nt * 16 + lm;
            shortx8 bh = *(const shortx8*)&uh[w * 64 + kk * 32 + lg * 8];
            shortx8 bl = *(const shortx8*)&ul[w * 64 + kk * 32 + lg * 8];
#pragma unroll
            for (int mt = 0; mt < 2; ++mt) {
                acc[mt][nt] = __builtin_amdgcn_mfma_f32_16x16x32_bf16(ah[mt], bh, acc[mt][nt], 0, 0, 0);
                acc[mt][nt] = __builtin_amdgcn_mfma_f32_16x16x32_bf16(ah[mt], bl, acc[mt][nt], 0, 0, 0);
                acc[mt][nt] = __builtin_amdgcn_mfma_f32_16x16x32_bf16(al[mt], bh, acc[mt][nt], 0, 0, 0);
            }
        }
    }

    float sum = 0.f, sq = 0.f;
#pragma unroll
    for (int mt = 0; mt < 2; ++mt)
#pragma unroll
        for (int nt = 0; nt < 16; ++nt) {
            int w = nt * 16 + lm;
#pragma unroll
            for (int r = 0; r < 4; ++r) {
                int row = wv * 32 + mt * 16 + lg * 4 + r;
                float v = acc[mt][nt][r];
                yout[(row0 + row) * NW + w] = v;
                sum += v;
                sq += v * v;
            }
        }
#pragma unroll
    for (int off = 32; off > 0; off >>= 1) {
        sum += __shfl_down(sum, off);
        sq += __shfl_down(sq, off);
    }
    if (lane == 0) { red[wv] = sum; red[4 + wv] = sq; }
    __syncthreads();
    if (t == 0) {
        int b = blk >> 7;
        atomicAdd(&gn_acc[b * 4 + 0], red[0] + red[1] + red[2] + red[3]);
        atomicAdd(&gn_acc[b * 4 + 1], red[4] + red[5] + red[6] + red[7]);
    }
}

// ---------------- K6: GN1 + residual + gelu + MLP via PLAIN-bf16 MFMA + GN2 stats
// Round 6: hi-only arithmetic (error ~0.0625 absmax, validated in prior session
// and round-0 line-468; threshold 0.28125). Round-3 LDS staging restored
// (coalesced 256B stage-1 reads — round-5's in-register variant doubled
// FETCH_SIZE to 254MB). Pre-split weights kept (round-4 win). LDS 39.3KB ->
// 4 blocks/CU.
// LDS layout (byte offsets):
//   vbuf @0      128 x 72 bf16 = 18432
//   w1b  @18432   32 x 72 bf16 = 4608
//   hbuf @23040  128 x 40 bf16 = 10240
//   w2b  @33280   64 x 40 bf16 = 5120   (end 38400)
//   params @38400 nw,nb(64ea) b1(32) b2(64) red(8) = 928  (end 39328)
//   outbuf @0     64 x 132 f32 = 33792  (aliases vbuf/w1b/hbuf/w2b-head; safe: sync)
__global__ __launch_bounds__(256, 4) void k6_mlp(const float* __restrict__ x,
                                                 const float* __restrict__ norm1_w,
                                                 const float* __restrict__ norm1_b,
                                                 const unsigned short* __restrict__ w1p_h,
                                                 const unsigned short* __restrict__ w2p_h,
                                                 const float* __restrict__ mlp_b1,
                                                 const float* __restrict__ mlp_b2,
                                                 float* __restrict__ y,
                                                 float* __restrict__ gn_acc) {
    __shared__ __align__(16) unsigned char smem[39328];
    unsigned short* vbuf = (unsigned short*)smem;
    unsigned short* w1b  = (unsigned short*)(smem + 18432);
    unsigned short* hbuf = (unsigned short*)(smem + 23040);
    unsigned short* w2b  = (unsigned short*)(smem + 33280);
    float* outbuf = (float*)smem;                 // alias (phase 2)
    float* nwl = (float*)(smem + 38400);
    float* nbl = nwl + 64;
    float* b1l = nbl + 64;
    float* b2l = b1l + 32;
    float* red = b2l + 64;

    int t = threadIdx.x;
    int blk = blockIdx.x;
    int b = blk >> 9;                  // 512 blocks per sample
    int pixbase = (blk & 511) * 128;
    size_t bbase = (size_t)b * NC * NHW + pixbase;

    if (t < 64) { nwl[t] = norm1_w[t]; nbl[t] = norm1_b[t]; b2l[t] = mlp_b2[t]; }
    if (t >= 64 && t < 96) b1l[t - 64] = mlp_b1[t - 64];
#pragma unroll
    for (int idx4 = t; idx4 < 512; idx4 += 256) {
        int r1 = idx4 >> 4, c1 = (idx4 & 15) << 2;
        *(ushort4*)&w1b[r1 * 72 + c1] = ((const ushort4*)w1p_h)[idx4];
        int r2 = idx4 >> 3, c2 = (idx4 & 7) << 2;
        *(ushort4*)&w2b[r2 * 40 + c2] = ((const ushort4*)w2p_h)[idx4];
    }
    __syncthreads();   // RACE FIX: params/weights visible before stage 1

    // --- stage 1: v = gelu(gn1(y)*nw+nb + x), bf16 into vbuf[pix][c]
    const float invN = 1.0f / (float)NPS;
    float m1 = gn_acc[b * 4 + 0] * invN;
    float var1 = gn_acc[b * 4 + 1] * invN - m1 * m1;
    float rs1 = rsqrtf(var1 + GN_EPS);
    {
        int p = t & 127;
        int c0 = (t >> 7) * 32;
        size_t base = bbase + (size_t)c0 * NHW + p;
#pragma unroll 8
        for (int ci = 0; ci < 32; ++ci) {
            float yv = y[base + (size_t)ci * NHW];
            float xv = x[base + (size_t)ci * NHW];
            int c = c0 + ci;
            float g = (yv - m1) * rs1 * nwl[c] + nbl[c] + xv;
            vbuf[p * 72 + c] = f2bf(gelu_f(g));
        }
    }
    __syncthreads();

    int lane = t & 63, wv = t >> 6;
    int lm = lane & 15, lg = lane >> 4;

    // --- layer 1 MFMA: h[128x32] = v[128x64] @ w1^T, + b1, gelu -> hbuf bf16
    floatx4 acc1[2][2] = {};
#pragma unroll
    for (int ks = 0; ks < 2; ++ks) {
        shortx8 a[2], bf[2];
#pragma unroll
        for (int mt = 0; mt < 2; ++mt)
            a[mt] = *(const shortx8*)&vbuf[(wv * 32 + mt * 16 + lm) * 72 + lg * 8 + ks * 32];
#pragma unroll
        for (int nt = 0; nt < 2; ++nt)
            bf[nt] = *(const shortx8*)&w1b[(nt * 16 + lm) * 72 + lg * 8 + ks * 32];
#pragma unroll
        for (int mt = 0; mt < 2; ++mt)
#pragma unroll
            for (int nt = 0; nt < 2; ++nt)
                acc1[mt][nt] = __builtin_amdgcn_mfma_f32_16x16x32_bf16(a[mt], bf[nt], acc1[mt][nt], 0, 0, 0);
    }
#pragma unroll
    for (int mt = 0; mt < 2; ++mt)
#pragma unroll
        for (int nt = 0; nt < 2; ++nt) {
            float b1v = b1l[nt * 16 + lm];
#pragma unroll
            for (int r = 0; r < 4; ++r) {
                float hv = gelu_f(acc1[mt][nt][r] + b1v);
                hbuf[(wv * 32 + mt * 16 + lg * 4 + r) * 40 + nt * 16 + lm] = f2bf(hv);
            }
        }
    __syncthreads();

    // --- layer 2 MFMA: out[128x64] = h[128x32] @ w2^T
    floatx4 acc2[2][4] = {};
    {
        shortx8 a2[2], b2f[4];
#pragma unroll
        for (int mt = 0; mt < 2; ++mt)
            a2[mt] = *(const shortx8*)&hbuf[(wv * 32 + mt * 16 + lm) * 40 + lg * 8];
#pragma unroll
        for (int nt = 0; nt < 4; ++nt)
            b2f[nt] = *(const shortx8*)&w2b[(nt * 16 + lm) * 40 + lg * 8];
#pragma unroll
        for (int mt = 0; mt < 2; ++mt)
#pragma unroll
            for (int nt = 0; nt < 4; ++nt)
                acc2[mt][nt] = __builtin_amdgcn_mfma_f32_16x16x32_bf16(a2[mt], b2f[nt], acc2[mt][nt], 0, 0, 0);
    }
    __syncthreads();   // all vbuf/hbuf/w2b reads done; outbuf may now clobber

    // --- write C-layout to fp32 outbuf[ch][pix] (+bias)
#pragma unroll
    for (int mt = 0; mt < 2; ++mt)
#pragma unroll
        for (int nt = 0; nt < 4; ++nt) {
            int ch = nt * 16 + lm;
            float b2v = b2l[ch];
#pragma unroll
            for (int r = 0; r < 4; ++r)
                outbuf[ch * 132 + wv * 32 + mt * 16 + lg * 4 + r] = acc2[mt][nt][r] + b2v;
        }
    __syncthreads();

    // --- coalesced global store + GN2 stats
    float sum = 0.f, sq = 0.f;
#pragma unroll
    for (int it = 0; it < 8; ++it) {
        int flat = it * 256 + t;
        int c = flat >> 5;
        int p4 = (flat & 31) * 4;
        float4 v = *(const float4*)&outbuf[c * 132 + p4];
        *(float4*)&y[bbase + (size_t)c * NHW + p4] = v;
        sum += v.x + v.y + v.z + v.w;
        sq += v.x * v.x + v.y * v.y + v.z * v.z + v.w * v.w;
    }
#pragma unroll
    for (int off = 32; off > 0; off >>= 1) {
        sum += __shfl_down(sum, off);
        sq += __shfl_down(sq, off);
    }
    if (lane == 0) { red[wv] = sum; red[4 + wv] = sq; }
    __syncthreads();
    if (t == 0) {
        atomicAdd(&gn_acc[b * 4 + 2], red[0] + red[1] + red[2] + red[3]);
        atomicAdd(&gn_acc[b * 4 + 3], red[4] + red[5] + red[6] + red[7]);
    }
}

// ---------------- K7: GN2 + FiLM + gelu(x) skip, elementwise, in-place
__global__ __launch_bounds__(256) void k7_final(const float* __restrict__ x,
                                                const float* __restrict__ gamma_bc,
                                                const float* __restrict__ beta_bc,
                                                const float* __restrict__ gn_acc,
                                                float* __restrict__ y) {
    size_t idx4 = (size_t)blockIdx.x * 256 + threadIdx.x;
    size_t base = idx4 * 4;
    int b = (int)(base >> 22);
    int c = (int)((base >> 16) & 63);
    const float invN = 1.0f / (float)NPS;
    float m2 = gn_acc[b * 4 + 2] * invN;
    float var2 = gn_acc[b * 4 + 3] * invN - m2 * m2;
    float rs2 = rsqrtf(var2 + GN_EPS);
    float g = gamma_bc[b * 64 + c];
    float be = beta_bc[b * 64 + c];
    float4 yv = ((float4*)y)[idx4];
    float4 xv = ((const float4*)x)[idx4];
    yv.x = g * ((yv.x - m2) * rs2) + be + gelu_f(xv.x);
    yv.y = g * ((yv.y - m2) * rs2) + be + gelu_f(xv.y);
    yv.z = g * ((yv.z - m2) * rs2) + be + gelu_f(xv.z);
    yv.w = g * ((yv.w - m2) * rs2) + be + gelu_f(xv.w);
    ((float4*)y)[idx4] = yv;
}

extern "C" void kernel_launch(void* const* d_in, const int* in_sizes, int n_in,
                              void* d_out, int out_size, void* d_ws, size_t ws_size,
                              hipStream_t stream) {
    (void)in_sizes; (void)n_in; (void)out_size; (void)ws_size;
    const float* x       = (const float*)d_in[0];
    const float* t_in    = (const float*)d_in[1];
    const float* w1r     = (const float*)d_in[2];
    const float* w1i     = (const float*)d_in[3];
    const float* w2r     = (const float*)d_in[4];
    const float* w2i     = (const float*)d_in[5];
    const float* norm1_w = (const float*)d_in[6];
    const float* norm1_b = (const float*)d_in[7];
    const float* mlp_w1  = (const float*)d_in[8];
    const float* mlp_b1  = (const float*)d_in[9];
    const float* mlp_w2  = (const float*)d_in[10];
    const float* mlp_b2  = (const float*)d_in[11];
    const float* gamma_w = (const float*)d_in[12];
    const float* gamma_b = (const float*)d_in[13];
    const float* beta_w  = (const float*)d_in[14];
    const float* beta_b  = (const float*)d_in[15];
    float* out = (float*)d_out;
    float* ws  = (float*)d_ws;

    float* gn_acc   = ws;            // 32
    float* gamma_bc = ws + 32;       // 512
    float* beta_bc  = ws + 544;      // 512
    float* xw_re    = ws + 2048;     // 4194304
    float* xw_im    = xw_re + 4194304;
    float* xf_re    = xw_im + 4194304;  // 1048576
    float* xf_im    = xf_re + 1048576;
    float* yf_re    = xf_im + 1048576;
    float* yf_im    = yf_re + 1048576;
    unsigned short* t1h = (unsigned short*)(yf_im + 1048576);
    unsigned short* t1l = t1h + 16384;
    unsigned short* uh  = t1l + 16384;
    unsigned short* ul  = uh + 16384;
    unsigned short* w1p_h = ul + 16384;     // 2048 each
    unsigned short* w1p_l = w1p_h + 2048;
    unsigned short* w2p_h = w1p_l + 2048;
    unsigned short* w2p_l = w2p_h + 2048;
    unsigned short* m2h = w2p_l + 2048;     // 65536 each
    unsigned short* m2l = m2h + 65536;
    unsigned short* m4h = m2l + 65536;
    unsigned short* m4l = m4h + 65536;

    k_tw<<<dim3(256), dim3(256), 0, stream>>>(t1h, t1l, uh, ul, m2h, m2l, m4h, m4l);
    k0_init<<<dim3(1), dim3(256), 0, stream>>>(t_in, gamma_w, gamma_b, beta_w, beta_b,
                                               mlp_w1, mlp_w2,
                                               gn_acc, gamma_bc, beta_bc,
                                               w1p_h, w1p_l, w2p_h, w2p_l);
    k1_dftw<<<dim3(1024), dim3(256), 0, stream>>>(x, t1h, t1l, xw_re, xw_im);
    k2_dfth<<<dim3(512), dim3(256), 0, stream>>>(xw_re, xw_im, m2h, m2l, xf_re, xf_im);
    k3_mix<<<dim3(1024), dim3(256), 0, stream>>>(xf_re, xf_im, w1r, w1i, w2r, w2i,
                                                 yf_re, yf_im);
    k4_idfth<<<dim3(512), dim3(256), 0, stream>>>(yf_re, yf_im, m4h, m4l, xw_re, xw_im);
    k5_irfftw<<<dim3(1024), dim3(256), 0, stream>>>(xw_re, xw_im, uh, ul, out, gn_acc);
    k6_mlp<<<dim3(4096), dim3(256), 0, stream>>>(x, norm1_w, norm1_b,
                                                 w1p_h, w2p_h,
                                                 mlp_b1, mlp_b2, out, gn_acc);
    k7_final<<<dim3(32768), dim3(256), 0, stream>>>(x, gamma_bc, beta_bc, gn_acc, out);
}